// Round 3
// baseline (1018.130 us; speedup 1.0000x reference)
//
#include <hip/hip_runtime.h>
#include <math.h>

#define H 32
#define NTHR 256

// softplus(beta=20): h = max(z,0) + log1p(exp(-|20z|))/20 ; s = sigmoid(20z)
__device__ __forceinline__ float act_hs(float z, float& s) {
    float bz = 20.0f * z;
    float e = __expf(-fabsf(bz));                 // (0,1]
    float r = __builtin_amdgcn_rcpf(1.0f + e);    // ~1ulp
    s = (bz >= 0.0f) ? r : (1.0f - r);
    return fmaxf(z, 0.0f) + 0.05f * __logf(1.0f + e);
}

// sigmoid(20z) with no select: exp overflow->inf, rcp(inf)->0 gives the
// correct saturation at both ends in IEEE fp32.
__device__ __forceinline__ float sigmoid20(float z) {
    float e = __expf(-20.0f * z);
    return __builtin_amdgcn_rcpf(1.0f + e);
}

__global__ void __launch_bounds__(NTHR)
presdiv_kernel(const float* __restrict__ x,
               const float* __restrict__ W1, const float* __restrict__ b1,
               const float* __restrict__ W2, const float* __restrict__ b2,
               const float* __restrict__ W3, const float* __restrict__ b3,
               const float* __restrict__ W4,
               float* __restrict__ out, int N)
{
    // Clamp instead of early-return: uniform control flow keeps weight loads
    // scalarizable (s_load), and duplicate tail writes are benign.
    int n = blockIdx.x * NTHR + threadIdx.x;
    n = (n < N) ? n : (N - 1);

    const float x0 = x[3 * n + 0];
    const float x1 = x[3 * n + 1];
    const float x2 = x[3 * n + 2];

    // ---------------- shared forward pass: keep only s1,s2,s3 --------------
    // Peak live here: s1+s2+h2+z3acc = 128 floats. Tangent phase: 96+64.
    // R0 spilled at ~230 live; this tops out ~175 incl. misc.
    float s1[H], s2[H], s3[H];
    {
        float h[H];  // h1, then reused
        #pragma unroll
        for (int j = 0; j < H; ++j) {
            float z = b1[j];
            z = fmaf(x0, W1[0 * H + j], z);
            z = fmaf(x1, W1[1 * H + j], z);
            z = fmaf(x2, W1[2 * H + j], z);
            h[j] = act_hs(z, s1[j]);
        }

        float z2[H];
        #pragma unroll
        for (int j = 0; j < H; ++j) z2[j] = b2[j];
        #pragma unroll
        for (int k = 0; k < H; ++k) {
            const float a = h[k];
            #pragma unroll
            for (int j = 0; j < H; ++j) z2[j] = fmaf(a, W2[k * H + j], z2[j]);
        }
        #pragma unroll
        for (int j = 0; j < H; ++j) h[j] = act_hs(z2[j], s2[j]);  // h := h2

        float z3[H];
        #pragma unroll
        for (int j = 0; j < H; ++j) z3[j] = b3[j];
        #pragma unroll
        for (int k = 0; k < H; ++k) {
            const float a = h[k];
            #pragma unroll
            for (int j = 0; j < H; ++j) z3[j] = fmaf(a, W3[k * H + j], z3[j]);
        }
        #pragma unroll
        for (int j = 0; j < H; ++j) s3[j] = sigmoid20(z3[j]);
    }

    // ---------------- 3 tangent passes, forward state shared ---------------
    float o0 = 0.f, o1 = 0.f, o2 = 0.f;
    #pragma unroll 1
    for (int i = 0; i < 3; ++i) {
        float t[H], u[H];
        #pragma unroll
        for (int j = 0; j < H; ++j) t[j] = s1[j] * W1[i * H + j];

        #pragma unroll
        for (int j = 0; j < H; ++j) u[j] = 0.f;
        #pragma unroll
        for (int k = 0; k < H; ++k) {
            const float a = t[k];
            #pragma unroll
            for (int j = 0; j < H; ++j) u[j] = fmaf(a, W2[k * H + j], u[j]);
        }
        #pragma unroll
        for (int j = 0; j < H; ++j) t[j] = s2[j] * u[j];

        #pragma unroll
        for (int j = 0; j < H; ++j) u[j] = 0.f;
        #pragma unroll
        for (int k = 0; k < H; ++k) {
            const float a = t[k];
            #pragma unroll
            for (int j = 0; j < H; ++j) u[j] = fmaf(a, W3[k * H + j], u[j]);
        }

        float J0 = 0.f, J1 = 0.f, J2 = 0.f;
        #pragma unroll
        for (int j = 0; j < H; ++j) {
            const float tt = s3[j] * u[j];
            J0 = fmaf(tt, W4[3 * j + 0], J0);
            J1 = fmaf(tt, W4[3 * j + 1], J1);
            J2 = fmaf(tt, W4[3 * j + 2], J2);
        }
        // out0 = J01 + J12; out1 = -J00 + J22; out2 = -J10 - J21
        if (i == 0)      { o1 -= J0; o2 -= J1; }
        else if (i == 1) { o0 += J0; o2 -= J2; }
        else             { o0 += J1; o1 += J2; }
    }

    out[3 * n + 0] = o0;
    out[3 * n + 1] = o1;
    out[3 * n + 2] = o2;
}

extern "C" void kernel_launch(void* const* d_in, const int* in_sizes, int n_in,
                              void* d_out, int out_size, void* d_ws, size_t ws_size,
                              hipStream_t stream)
{
    const float* x  = (const float*)d_in[0];
    const float* W1 = (const float*)d_in[1];
    const float* b1 = (const float*)d_in[2];
    const float* W2 = (const float*)d_in[3];
    const float* b2 = (const float*)d_in[4];
    const float* W3 = (const float*)d_in[5];
    const float* b3 = (const float*)d_in[6];
    const float* W4 = (const float*)d_in[7];
    // d_in[8] = b4 unused: constant offset cancels in the Jacobian.
    float* out = (float*)d_out;

    const int N = in_sizes[0] / 3;
    const int blocks = (N + NTHR - 1) / NTHR;
    presdiv_kernel<<<blocks, NTHR, 0, stream>>>(x, W1, b1, W2, b2, W3, b3, W4, out, N);
}

// Round 4
// 195.805 us; speedup vs baseline: 5.1997x; 5.1997x over previous
//
#include <hip/hip_runtime.h>
#include <math.h>

#define NTHR 256
#define WAVES_PER_BLOCK 4

typedef __attribute__((ext_vector_type(8))) short bf16x8;   // 8 bf16 bit-patterns (4 VGPRs)
typedef __attribute__((ext_vector_type(4))) float f32x4;    // MFMA C/D frag

// softplus(beta=20): h = max(z,0) + log1p(exp(-|20z|))/20 ; s = sigmoid(20z)
static __device__ __forceinline__ float act_hs(float z, float& s) {
    float bz = 20.0f * z;
    float e = __expf(-fabsf(bz));
    float r = __builtin_amdgcn_rcpf(1.0f + e);
    s = (bz >= 0.0f) ? r : (1.0f - r);
    return fmaxf(z, 0.0f) + 0.05f * __logf(1.0f + e);
}
static __device__ __forceinline__ float sigmoid20(float z) {
    float e = __expf(-20.0f * z);                 // overflow->inf, rcp->0: correct saturation
    return __builtin_amdgcn_rcpf(1.0f + e);
}

// fp32 -> bf16 hi + bf16 lo (truncation split; combined rel err ~2^-16)
static __device__ __forceinline__ void split1(float v, short& hi, short& lo) {
    unsigned u = __builtin_bit_cast(unsigned, v);
    float hf = __builtin_bit_cast(float, u & 0xFFFF0000u);
    hi = (short)(u >> 16);
    lo = (short)(__builtin_bit_cast(unsigned, v - hf) >> 16);
}

static __device__ __forceinline__ void split8(const float* v, bf16x8& bh, bf16x8& bl) {
    #pragma unroll
    for (int j = 0; j < 8; ++j) {
        short hi, lo; split1(v[j], hi, lo);
        bh[j] = hi; bl[j] = lo;
    }
}

static __device__ __forceinline__ float bperm(int addr, float v) {
    return __builtin_bit_cast(float,
        __builtin_amdgcn_ds_bpermute(addr, __builtin_bit_cast(int, v)));
}

// fp32-split matmul accumulate: D += Whi*Bhi + Whi*Blo + Wlo*Bhi  (drop lo*lo)
static __device__ __forceinline__ f32x4 mfma3(bf16x8 wh, bf16x8 wl, bf16x8 bh, bf16x8 bl, f32x4 c) {
    c = __builtin_amdgcn_mfma_f32_16x16x32_bf16(wh, bh, c, 0, 0, 0);
    c = __builtin_amdgcn_mfma_f32_16x16x32_bf16(wh, bl, c, 0, 0, 0);
    c = __builtin_amdgcn_mfma_f32_16x16x32_bf16(wl, bh, c, 0, 0, 0);
    return c;
}

// C-layout (2 half-frags: rows 0-15, 16-31; lane holds col n, rows 4g+r) ->
// B-layout (lane holds col n, rows 8g..8g+7), via register crossbar.
static __device__ __forceinline__ void c2b(f32x4 c0, f32x4 c1,
                                           int addrA, int addrB, bool hiHalf,
                                           bf16x8& bh, bf16x8& bl) {
    #pragma unroll
    for (int j = 0; j < 8; ++j) {
        const int reg = j & 3;
        const int addr = (j < 4) ? addrA : addrB;
        float a0 = bperm(addr, c0[reg]);
        float a1 = bperm(addr, c1[reg]);
        float v = hiHalf ? a1 : a0;
        short hi, lo; split1(v, hi, lo);
        bh[j] = hi; bl[j] = lo;
    }
}

__global__ void __launch_bounds__(NTHR)
presdiv_kernel(const float* __restrict__ x,
               const float* __restrict__ W1, const float* __restrict__ b1,
               const float* __restrict__ W2, const float* __restrict__ b2,
               const float* __restrict__ W3, const float* __restrict__ b3,
               const float* __restrict__ W4,
               float* __restrict__ out, int N)
{
    const int lane = threadIdx.x & 63;
    const int wid  = threadIdx.x >> 6;
    const int n16  = lane & 15;        // sample-within-tile / MFMA col
    const int g    = lane >> 4;        // quad
    const bool hiHalf = (g >= 2);
    // bpermute source-lane byte addresses for the C->B transform
    const int addrA = ((2 * (g & 1)) * 16 + n16) * 4;
    const int addrB = addrA + 64;

    // ---- persistent weights (per lane) ----
    // A-frags: A[m=n16][k=8g+j] = W[k][16h+n16], split hi/lo bf16.
    bf16x8 w2h[2], w2l[2], w3h[2], w3l[2];
    #pragma unroll
    for (int h = 0; h < 2; ++h) {
        #pragma unroll
        for (int j = 0; j < 8; ++j) {
            short hi, lo;
            split1(W2[(g * 8 + j) * 32 + 16 * h + n16], hi, lo);
            w2h[h][j] = hi; w2l[h][j] = lo;
            split1(W3[(g * 8 + j) * 32 + 16 * h + n16], hi, lo);
            w3h[h][j] = hi; w3l[h][j] = lo;
        }
    }
    // layer-1 rows this lane produces (features k = 8g+j), exact fp32
    float w1r[3][8], bb1[8];
    #pragma unroll
    for (int j = 0; j < 8; ++j) {
        bb1[j] = b1[g * 8 + j];
        #pragma unroll
        for (int d = 0; d < 3; ++d) w1r[d][j] = W1[d * 32 + g * 8 + j];
    }
    // C-layout rows this lane holds (4g+r, +16h): biases + W4 rows
    float bb2[2][4], bb3[2][4], w4r[2][4][3];
    #pragma unroll
    for (int h = 0; h < 2; ++h)
        #pragma unroll
        for (int r = 0; r < 4; ++r) {
            const int row = 16 * h + 4 * g + r;
            bb2[h][r] = b2[row];
            bb3[h][r] = b3[row];
            #pragma unroll
            for (int k = 0; k < 3; ++k) w4r[h][r][k] = W4[row * 3 + k];
        }

    const int ntiles = (N + 15) >> 4;
    const int nwaves = gridDim.x * WAVES_PER_BLOCK;
    const f32x4 vzero = {0.f, 0.f, 0.f, 0.f};

    for (int tile = blockIdx.x * WAVES_PER_BLOCK + wid; tile < ntiles; tile += nwaves) {
        int s = tile * 16 + n16;
        if (s >= N) s = N - 1;
        const float x0 = x[3 * s + 0];
        const float x1 = x[3 * s + 1];
        const float x2 = x[3 * s + 2];

        // ---- layer 1 (exact fp32), directly in B-layout ----
        float vF[8], v0[8], v1[8], v2[8];
        #pragma unroll
        for (int j = 0; j < 8; ++j) {
            float z = bb1[j];
            z = fmaf(x0, w1r[0][j], z);
            z = fmaf(x1, w1r[1][j], z);
            z = fmaf(x2, w1r[2][j], z);
            float sg; vF[j] = act_hs(z, sg);
            v0[j] = sg * w1r[0][j];
            v1[j] = sg * w1r[1][j];
            v2[j] = sg * w1r[2][j];
        }

        // ---- layer 2: 4 streams x 2 halves x mfma3 ----
        f32x4 aF[2], a0[2], a1[2], a2[2];
        aF[0] = (f32x4){bb2[0][0], bb2[0][1], bb2[0][2], bb2[0][3]};
        aF[1] = (f32x4){bb2[1][0], bb2[1][1], bb2[1][2], bb2[1][3]};
        a0[0] = a0[1] = a1[0] = a1[1] = a2[0] = a2[1] = vzero;

        bf16x8 bh, bl;
        split8(vF, bh, bl);
        aF[0] = mfma3(w2h[0], w2l[0], bh, bl, aF[0]);
        aF[1] = mfma3(w2h[1], w2l[1], bh, bl, aF[1]);
        split8(v0, bh, bl);
        a0[0] = mfma3(w2h[0], w2l[0], bh, bl, a0[0]);
        a0[1] = mfma3(w2h[1], w2l[1], bh, bl, a0[1]);
        split8(v1, bh, bl);
        a1[0] = mfma3(w2h[0], w2l[0], bh, bl, a1[0]);
        a1[1] = mfma3(w2h[1], w2l[1], bh, bl, a1[1]);
        split8(v2, bh, bl);
        a2[0] = mfma3(w2h[0], w2l[0], bh, bl, a2[0]);
        a2[1] = mfma3(w2h[1], w2l[1], bh, bl, a2[1]);

        // ---- boundary: act + diag-scale in C-layout ----
        f32x4 hC[2], tC0[2], tC1[2], tC2[2];
        #pragma unroll
        for (int h = 0; h < 2; ++h)
            #pragma unroll
            for (int r = 0; r < 4; ++r) {
                float s2v;
                hC[h][r]  = act_hs(aF[h][r], s2v);
                tC0[h][r] = s2v * a0[h][r];
                tC1[h][r] = s2v * a1[h][r];
                tC2[h][r] = s2v * a2[h][r];
            }

        // ---- layer 3 ----
        f32x4 zF[2], u0[2], u1[2], u2[2];
        zF[0] = (f32x4){bb3[0][0], bb3[0][1], bb3[0][2], bb3[0][3]};
        zF[1] = (f32x4){bb3[1][0], bb3[1][1], bb3[1][2], bb3[1][3]};
        u0[0] = u0[1] = u1[0] = u1[1] = u2[0] = u2[1] = vzero;

        c2b(hC[0], hC[1], addrA, addrB, hiHalf, bh, bl);
        zF[0] = mfma3(w3h[0], w3l[0], bh, bl, zF[0]);
        zF[1] = mfma3(w3h[1], w3l[1], bh, bl, zF[1]);
        c2b(tC0[0], tC0[1], addrA, addrB, hiHalf, bh, bl);
        u0[0] = mfma3(w3h[0], w3l[0], bh, bl, u0[0]);
        u0[1] = mfma3(w3h[1], w3l[1], bh, bl, u0[1]);
        c2b(tC1[0], tC1[1], addrA, addrB, hiHalf, bh, bl);
        u1[0] = mfma3(w3h[0], w3l[0], bh, bl, u1[0]);
        u1[1] = mfma3(w3h[1], w3l[1], bh, bl, u1[1]);
        c2b(tC2[0], tC2[1], addrA, addrB, hiHalf, bh, bl);
        u2[0] = mfma3(w3h[0], w3l[0], bh, bl, u2[0]);
        u2[1] = mfma3(w3h[1], w3l[1], bh, bl, u2[1]);

        // ---- layer 4 + trace combine (exact fp32, partial over held rows) ----
        float J[3][3];  // J[i][k] = dv_k/dx_i
        #pragma unroll
        for (int i = 0; i < 3; ++i)
            #pragma unroll
            for (int k = 0; k < 3; ++k) J[i][k] = 0.f;

        #pragma unroll
        for (int h = 0; h < 2; ++h)
            #pragma unroll
            for (int r = 0; r < 4; ++r) {
                const float s3v = sigmoid20(zF[h][r]);
                const float t0v = s3v * u0[h][r];
                const float t1v = s3v * u1[h][r];
                const float t2v = s3v * u2[h][r];
                #pragma unroll
                for (int k = 0; k < 3; ++k) {
                    J[0][k] = fmaf(t0v, w4r[h][r][k], J[0][k]);
                    J[1][k] = fmaf(t1v, w4r[h][r][k], J[1][k]);
                    J[2][k] = fmaf(t2v, w4r[h][r][k], J[2][k]);
                }
            }

        // reduce partials across the 4 quads holding the same sample col
        #pragma unroll
        for (int i = 0; i < 3; ++i)
            #pragma unroll
            for (int k = 0; k < 3; ++k) {
                float v = J[i][k];
                v += __shfl_xor(v, 16);
                v += __shfl_xor(v, 32);
                J[i][k] = v;
            }

        if (g == 0) {
            out[3 * s + 0] =  J[1][0] + J[2][1];
            out[3 * s + 1] = -J[0][0] + J[2][2];
            out[3 * s + 2] = -J[0][1] - J[1][2];
        }
    }
}

extern "C" void kernel_launch(void* const* d_in, const int* in_sizes, int n_in,
                              void* d_out, int out_size, void* d_ws, size_t ws_size,
                              hipStream_t stream)
{
    const float* x  = (const float*)d_in[0];
    const float* W1 = (const float*)d_in[1];
    const float* b1 = (const float*)d_in[2];
    const float* W2 = (const float*)d_in[3];
    const float* b2 = (const float*)d_in[4];
    const float* W3 = (const float*)d_in[5];
    const float* b3 = (const float*)d_in[6];
    const float* W4 = (const float*)d_in[7];
    // d_in[8] = b4 unused: constant offset cancels in the Jacobian.
    float* out = (float*)d_out;

    const int N = in_sizes[0] / 3;
    const int blocks = 2048;   // grid-stride; amortizes weight-frag setup
    presdiv_kernel<<<blocks, NTHR, 0, stream>>>(x, W1, b1, W2, b2, W3, b3, W4, out, N);
}

// Round 5
// 180.003 us; speedup vs baseline: 5.6562x; 1.0878x over previous
//
#include <hip/hip_runtime.h>
#include <math.h>

#define NTHR 256
#define WAVES_PER_BLOCK 4

typedef __attribute__((ext_vector_type(8))) short bf16x8;   // 8 bf16 bit-patterns (4 VGPRs)
typedef __attribute__((ext_vector_type(4))) float f32x4;    // MFMA C/D frag

// softplus(beta=20): h = max(z,0) + log1p(exp(-|20z|))/20 ; s = sigmoid(20z)
static __device__ __forceinline__ float act_hs(float z, float& s) {
    float bz = 20.0f * z;
    float e = __expf(-fabsf(bz));
    float r = __builtin_amdgcn_rcpf(1.0f + e);
    s = (bz >= 0.0f) ? r : (1.0f - r);
    return fmaxf(z, 0.0f) + 0.05f * __logf(1.0f + e);
}
static __device__ __forceinline__ float sigmoid20(float z) {
    float e = __expf(-20.0f * z);                 // overflow->inf, rcp->0: correct saturation
    return __builtin_amdgcn_rcpf(1.0f + e);
}

// fp32 -> bf16 hi + bf16 lo (truncation split; combined rel err ~2^-16)
static __device__ __forceinline__ void split1(float v, short& hi, short& lo) {
    unsigned u = __builtin_bit_cast(unsigned, v);
    float hf = __builtin_bit_cast(float, u & 0xFFFF0000u);
    hi = (short)(u >> 16);
    lo = (short)(__builtin_bit_cast(unsigned, v - hf) >> 16);
}

static __device__ __forceinline__ void split8(const float* v, bf16x8& bh, bf16x8& bl) {
    #pragma unroll
    for (int j = 0; j < 8; ++j) {
        short hi, lo; split1(v[j], hi, lo);
        bh[j] = hi; bl[j] = lo;
    }
}

// Split a C-frag pair (rows 0-15 half, rows 16-31 half) straight into a
// layer-3 B-operand. Valid because layer-3's A-fragment is loaded with the
// matching K-permutation f(g,j) = j<4 ? 4g+j : 16+4g+(j-4).
static __device__ __forceinline__ void split_cc(const f32x4& c0, const f32x4& c1,
                                                bf16x8& bh, bf16x8& bl) {
    #pragma unroll
    for (int r = 0; r < 4; ++r) {
        short hi, lo;
        split1(c0[r], hi, lo); bh[r]     = hi; bl[r]     = lo;
        split1(c1[r], hi, lo); bh[r + 4] = hi; bl[r + 4] = lo;
    }
}

// fp32-split matmul accumulate: D += Whi*Bhi + Whi*Blo + Wlo*Bhi  (drop lo*lo)
static __device__ __forceinline__ f32x4 mfma3(bf16x8 wh, bf16x8 wl, bf16x8 bh, bf16x8 bl, f32x4 c) {
    c = __builtin_amdgcn_mfma_f32_16x16x32_bf16(wh, bh, c, 0, 0, 0);
    c = __builtin_amdgcn_mfma_f32_16x16x32_bf16(wh, bl, c, 0, 0, 0);
    c = __builtin_amdgcn_mfma_f32_16x16x32_bf16(wl, bh, c, 0, 0, 0);
    return c;
}

__global__ void __launch_bounds__(NTHR)
presdiv_kernel(const float* __restrict__ x,
               const float* __restrict__ W1, const float* __restrict__ b1,
               const float* __restrict__ W2, const float* __restrict__ b2,
               const float* __restrict__ W3, const float* __restrict__ b3,
               const float* __restrict__ W4,
               float* __restrict__ out, int N)
{
    const int lane = threadIdx.x & 63;
    const int wid  = threadIdx.x >> 6;
    const int n16  = lane & 15;        // sample-within-tile / MFMA col
    const int g    = lane >> 4;        // quad

    // ---- persistent weights (per lane) ----
    // Layer-2 A-frag, standard K: slot (g,j) holds k = 8g+j.
    // Layer-3 A-frag, permuted K: slot (g,j) holds k = f(g,j) so that the
    // layer-2 C-output frags are directly the layer-3 B-operands.
    bf16x8 w2h[2], w2l[2], w3h[2], w3l[2];
    #pragma unroll
    for (int h = 0; h < 2; ++h) {
        #pragma unroll
        for (int j = 0; j < 8; ++j) {
            short hi, lo;
            const int k2 = g * 8 + j;
            split1(W2[k2 * 32 + 16 * h + n16], hi, lo);
            w2h[h][j] = hi; w2l[h][j] = lo;
            const int k3 = (j < 4) ? (4 * g + j) : (16 + 4 * g + (j - 4));
            split1(W3[k3 * 32 + 16 * h + n16], hi, lo);
            w3h[h][j] = hi; w3l[h][j] = lo;
        }
    }
    // layer-1 rows this lane produces (features k = 8g+j), exact fp32
    float w1r[3][8], bb1[8];
    #pragma unroll
    for (int j = 0; j < 8; ++j) {
        bb1[j] = b1[g * 8 + j];
        #pragma unroll
        for (int d = 0; d < 3; ++d) w1r[d][j] = W1[d * 32 + g * 8 + j];
    }
    // C-layout rows this lane holds (16h + 4g + r): biases + W4 rows
    float bb2[2][4], bb3[2][4], w4r[2][4][3];
    #pragma unroll
    for (int h = 0; h < 2; ++h)
        #pragma unroll
        for (int r = 0; r < 4; ++r) {
            const int row = 16 * h + 4 * g + r;
            bb2[h][r] = b2[row];
            bb3[h][r] = b3[row];
            #pragma unroll
            for (int k = 0; k < 3; ++k) w4r[h][r][k] = W4[row * 3 + k];
        }

    const int ntiles = (N + 15) >> 4;
    const int nwaves = gridDim.x * WAVES_PER_BLOCK;
    const f32x4 vzero = {0.f, 0.f, 0.f, 0.f};

    for (int tile = blockIdx.x * WAVES_PER_BLOCK + wid; tile < ntiles; tile += nwaves) {
        int s = tile * 16 + n16;
        if (s >= N) s = N - 1;
        const float x0 = x[3 * s + 0];
        const float x1 = x[3 * s + 1];
        const float x2 = x[3 * s + 2];

        // ---- layer 1 (exact fp32), directly in B-layout ----
        float vF[8], v0[8], v1[8], v2[8];
        #pragma unroll
        for (int j = 0; j < 8; ++j) {
            float z = bb1[j];
            z = fmaf(x0, w1r[0][j], z);
            z = fmaf(x1, w1r[1][j], z);
            z = fmaf(x2, w1r[2][j], z);
            float sg; vF[j] = act_hs(z, sg);
            v0[j] = sg * w1r[0][j];
            v1[j] = sg * w1r[1][j];
            v2[j] = sg * w1r[2][j];
        }

        // ---- layer 2: 4 streams x 2 halves x mfma3 ----
        f32x4 aF[2], a0[2], a1[2], a2[2];
        aF[0] = (f32x4){bb2[0][0], bb2[0][1], bb2[0][2], bb2[0][3]};
        aF[1] = (f32x4){bb2[1][0], bb2[1][1], bb2[1][2], bb2[1][3]};
        a0[0] = a0[1] = a1[0] = a1[1] = a2[0] = a2[1] = vzero;

        bf16x8 bh, bl;
        split8(vF, bh, bl);
        aF[0] = mfma3(w2h[0], w2l[0], bh, bl, aF[0]);
        aF[1] = mfma3(w2h[1], w2l[1], bh, bl, aF[1]);
        split8(v0, bh, bl);
        a0[0] = mfma3(w2h[0], w2l[0], bh, bl, a0[0]);
        a0[1] = mfma3(w2h[1], w2l[1], bh, bl, a0[1]);
        split8(v1, bh, bl);
        a1[0] = mfma3(w2h[0], w2l[0], bh, bl, a1[0]);
        a1[1] = mfma3(w2h[1], w2l[1], bh, bl, a1[1]);
        split8(v2, bh, bl);
        a2[0] = mfma3(w2h[0], w2l[0], bh, bl, a2[0]);
        a2[1] = mfma3(w2h[1], w2l[1], bh, bl, a2[1]);

        // ---- boundary: act + diag-scale, in C-layout (stays in-register) ----
        #pragma unroll
        for (int h = 0; h < 2; ++h)
            #pragma unroll
            for (int r = 0; r < 4; ++r) {
                float s2v;
                aF[h][r] = act_hs(aF[h][r], s2v);   // h2
                a0[h][r] *= s2v;
                a1[h][r] *= s2v;
                a2[h][r] *= s2v;
            }

        // ---- layer 3: C-frags feed B directly (K-permuted weights) ----
        f32x4 zF[2], u0[2], u1[2], u2[2];
        zF[0] = (f32x4){bb3[0][0], bb3[0][1], bb3[0][2], bb3[0][3]};
        zF[1] = (f32x4){bb3[1][0], bb3[1][1], bb3[1][2], bb3[1][3]};
        u0[0] = u0[1] = u1[0] = u1[1] = u2[0] = u2[1] = vzero;

        split_cc(aF[0], aF[1], bh, bl);
        zF[0] = mfma3(w3h[0], w3l[0], bh, bl, zF[0]);
        zF[1] = mfma3(w3h[1], w3l[1], bh, bl, zF[1]);
        split_cc(a0[0], a0[1], bh, bl);
        u0[0] = mfma3(w3h[0], w3l[0], bh, bl, u0[0]);
        u0[1] = mfma3(w3h[1], w3l[1], bh, bl, u0[1]);
        split_cc(a1[0], a1[1], bh, bl);
        u1[0] = mfma3(w3h[0], w3l[0], bh, bl, u1[0]);
        u1[1] = mfma3(w3h[1], w3l[1], bh, bl, u1[1]);
        split_cc(a2[0], a2[1], bh, bl);
        u2[0] = mfma3(w3h[0], w3l[0], bh, bl, u2[0]);
        u2[1] = mfma3(w3h[1], w3l[1], bh, bl, u2[1]);

        // ---- layer 4 fused with trace combine (6 FMA/row) ----
        // out0 = J[1][0]+J[2][1]; out1 = -J[0][0]+J[2][2]; out2 = -J[0][1]-J[1][2]
        float o0 = 0.f, o1 = 0.f, o2 = 0.f;
        #pragma unroll
        for (int h = 0; h < 2; ++h)
            #pragma unroll
            for (int r = 0; r < 4; ++r) {
                const float s3v = sigmoid20(zF[h][r]);
                const float t0v = s3v * u0[h][r];
                const float t1v = s3v * u1[h][r];
                const float t2v = s3v * u2[h][r];
                const float w0 = w4r[h][r][0], w1 = w4r[h][r][1], w2 = w4r[h][r][2];
                o0 = fmaf(t1v, w0, fmaf(t2v, w1, o0));
                o1 = fmaf(-t0v, w0, fmaf(t2v, w2, o1));
                o2 = fmaf(-t0v, w1, fmaf(-t1v, w2, o2));
            }

        // reduce partials across the 4 quads holding the same sample col
        o0 += __shfl_xor(o0, 16); o0 += __shfl_xor(o0, 32);
        o1 += __shfl_xor(o1, 16); o1 += __shfl_xor(o1, 32);
        o2 += __shfl_xor(o2, 16); o2 += __shfl_xor(o2, 32);

        if (g == 0) {
            out[3 * s + 0] = o0;
            out[3 * s + 1] = o1;
            out[3 * s + 2] = o2;
        }
    }
}

extern "C" void kernel_launch(void* const* d_in, const int* in_sizes, int n_in,
                              void* d_out, int out_size, void* d_ws, size_t ws_size,
                              hipStream_t stream)
{
    const float* x  = (const float*)d_in[0];
    const float* W1 = (const float*)d_in[1];
    const float* b1 = (const float*)d_in[2];
    const float* W2 = (const float*)d_in[3];
    const float* b2 = (const float*)d_in[4];
    const float* W3 = (const float*)d_in[5];
    const float* b3 = (const float*)d_in[6];
    const float* W4 = (const float*)d_in[7];
    // d_in[8] = b4 unused: constant offset cancels in the Jacobian.
    float* out = (float*)d_out;

    const int N = in_sizes[0] / 3;
    const int blocks = 2048;   // grid-stride; amortizes weight-frag setup
    presdiv_kernel<<<blocks, NTHR, 0, stream>>>(x, W1, b1, W2, b2, W3, b3, W4, out, N);
}

// Round 7
// 161.465 us; speedup vs baseline: 6.3056x; 1.1148x over previous
//
#include <hip/hip_runtime.h>
#include <math.h>

#define NTHR 256
#define WAVES_PER_BLOCK 4

typedef __attribute__((ext_vector_type(8))) short bf16x8;   // 8 bf16 bit-patterns (4 VGPRs)
typedef __attribute__((ext_vector_type(4))) float f32x4;    // MFMA C/D frag

#define CEXP 28.85390082f     // 20 * log2(e)
#define KLOG 0.03465735903f   // ln(2) / 20

// raw gfx950 transcendental builtins: v_exp_f32 is 2^x, v_log_f32 is log2(x)
#define EXP2F(v) __builtin_amdgcn_exp2f(v)
#define LOG2F(v) __builtin_amdgcn_logf(v)

// softplus(beta=20): h = max(z,0) + (ln2/20)*log2(1+e), e = exp2(-|20z*log2e|)
// s = sigmoid(20z) via select on r = 1/(1+e)
static __device__ __forceinline__ float act_hs(float z, float& s) {
    float cz = CEXP * z;
    float e  = EXP2F(-fabsf(cz));                 // 1 exp2, input modifiers fold
    float p  = 1.0f + e;
    float r  = __builtin_amdgcn_rcpf(p);
    s = (z >= 0.0f) ? r : (1.0f - r);
    return fmaxf(z, 0.0f) + KLOG * LOG2F(p);
}

// full-range, select-free: exp2 overflow->inf, rcp(inf)->0 saturates correctly
static __device__ __forceinline__ float sigmoid20(float z) {
    float e = EXP2F(-CEXP * z);
    return __builtin_amdgcn_rcpf(1.0f + e);
}

// pack hi16(a) into low short, hi16(b) into high short: one v_perm_b32
static __device__ __forceinline__ unsigned hipack(float a, float b) {
    return __builtin_amdgcn_perm(__builtin_bit_cast(unsigned, b),
                                 __builtin_bit_cast(unsigned, a), 0x07060302u);
}

// fp32 pair -> packed bf16 hi pair + packed bf16 lo pair (6 instr total)
static __device__ __forceinline__ void splitpair(float a, float b, unsigned& ph, unsigned& pl) {
    float ah = __builtin_bit_cast(float, __builtin_bit_cast(unsigned, a) & 0xFFFF0000u);
    float bh = __builtin_bit_cast(float, __builtin_bit_cast(unsigned, b) & 0xFFFF0000u);
    ph = hipack(a, b);
    pl = hipack(a - ah, b - bh);
}

static __device__ __forceinline__ void split8(const float* v, bf16x8& bh, bf16x8& bl) {
    unsigned h[4], l[4];
    #pragma unroll
    for (int p = 0; p < 4; ++p) splitpair(v[2 * p], v[2 * p + 1], h[p], l[p]);
    typedef __attribute__((ext_vector_type(4))) unsigned uint4v;
    bh = __builtin_bit_cast(bf16x8, (uint4v){h[0], h[1], h[2], h[3]});
    bl = __builtin_bit_cast(bf16x8, (uint4v){l[0], l[1], l[2], l[3]});
}

// C-frag pair (rows 0-15 half, rows 16-31 half) -> layer-3 B operand.
// Valid because layer-3's A-frag K-index is permuted to match: f(g,j) =
// j<4 ? 4g+j : 16+4g+(j-4).
static __device__ __forceinline__ void split_cc(const f32x4& c0, const f32x4& c1,
                                                bf16x8& bh, bf16x8& bl) {
    unsigned h[4], l[4];
    splitpair(c0[0], c0[1], h[0], l[0]);
    splitpair(c0[2], c0[3], h[1], l[1]);
    splitpair(c1[0], c1[1], h[2], l[2]);
    splitpair(c1[2], c1[3], h[3], l[3]);
    typedef __attribute__((ext_vector_type(4))) unsigned uint4v;
    bh = __builtin_bit_cast(bf16x8, (uint4v){h[0], h[1], h[2], h[3]});
    bl = __builtin_bit_cast(bf16x8, (uint4v){l[0], l[1], l[2], l[3]});
}

// setup-time scalar split
static __device__ __forceinline__ void split1(float v, short& hi, short& lo) {
    unsigned u = __builtin_bit_cast(unsigned, v);
    float hf = __builtin_bit_cast(float, u & 0xFFFF0000u);
    hi = (short)(u >> 16);
    lo = (short)(__builtin_bit_cast(unsigned, v - hf) >> 16);
}

// fp32-split matmul accumulate: D += Whi*Bhi + Whi*Blo + Wlo*Bhi  (drop lo*lo)
static __device__ __forceinline__ f32x4 mfma3(bf16x8 wh, bf16x8 wl, bf16x8 bh, bf16x8 bl, f32x4 c) {
    c = __builtin_amdgcn_mfma_f32_16x16x32_bf16(wh, bh, c, 0, 0, 0);
    c = __builtin_amdgcn_mfma_f32_16x16x32_bf16(wh, bl, c, 0, 0, 0);
    c = __builtin_amdgcn_mfma_f32_16x16x32_bf16(wl, bh, c, 0, 0, 0);
    return c;
}

__global__ void __launch_bounds__(NTHR)
presdiv_kernel(const float* __restrict__ x,
               const float* __restrict__ W1, const float* __restrict__ b1,
               const float* __restrict__ W2, const float* __restrict__ b2,
               const float* __restrict__ W3, const float* __restrict__ b3,
               const float* __restrict__ W4,
               float* __restrict__ out, int N)
{
    const int lane = threadIdx.x & 63;
    const int wid  = threadIdx.x >> 6;
    const int n16  = lane & 15;        // sample-within-tile / MFMA col
    const int g    = lane >> 4;        // quad

    // ---- persistent weights (per lane) ----
    bf16x8 w2h[2], w2l[2], w3h[2], w3l[2];
    #pragma unroll
    for (int h = 0; h < 2; ++h) {
        #pragma unroll
        for (int j = 0; j < 8; ++j) {
            short hi, lo;
            const int k2 = g * 8 + j;
            split1(W2[k2 * 32 + 16 * h + n16], hi, lo);
            w2h[h][j] = hi; w2l[h][j] = lo;
            const int k3 = (j < 4) ? (4 * g + j) : (16 + 4 * g + (j - 4));
            split1(W3[k3 * 32 + 16 * h + n16], hi, lo);
            w3h[h][j] = hi; w3l[h][j] = lo;
        }
    }
    float w1r[3][8], bb1[8];
    #pragma unroll
    for (int j = 0; j < 8; ++j) {
        bb1[j] = b1[g * 8 + j];
        #pragma unroll
        for (int d = 0; d < 3; ++d) w1r[d][j] = W1[d * 32 + g * 8 + j];
    }
    float bb2[2][4], bb3[2][4], w4r[2][4][3];
    #pragma unroll
    for (int h = 0; h < 2; ++h)
        #pragma unroll
        for (int r = 0; r < 4; ++r) {
            const int row = 16 * h + 4 * g + r;
            bb2[h][r] = b2[row];
            bb3[h][r] = b3[row];
            #pragma unroll
            for (int k = 0; k < 3; ++k) w4r[h][r][k] = W4[row * 3 + k];
        }

    const int ntiles = (N + 15) >> 4;
    const int nwaves = gridDim.x * WAVES_PER_BLOCK;
    const f32x4 vzero = {0.f, 0.f, 0.f, 0.f};

    for (int tile = blockIdx.x * WAVES_PER_BLOCK + wid; tile < ntiles; tile += nwaves) {
        int s = tile * 16 + n16;
        if (s >= N) s = N - 1;
        const float x0 = x[3 * s + 0];
        const float x1 = x[3 * s + 1];
        const float x2 = x[3 * s + 2];

        // ---- layer 1 (exact fp32), directly in B-layout ----
        float vF[8], v0[8], v1[8], v2[8];
        #pragma unroll
        for (int j = 0; j < 8; ++j) {
            float z = bb1[j];
            z = fmaf(x0, w1r[0][j], z);
            z = fmaf(x1, w1r[1][j], z);
            z = fmaf(x2, w1r[2][j], z);
            float sg; vF[j] = act_hs(z, sg);
            v0[j] = sg * w1r[0][j];
            v1[j] = sg * w1r[1][j];
            v2[j] = sg * w1r[2][j];
        }

        // ---- layer 2: 4 streams x 2 halves x mfma3 ----
        f32x4 aF[2], a0[2], a1[2], a2[2];
        aF[0] = (f32x4){bb2[0][0], bb2[0][1], bb2[0][2], bb2[0][3]};
        aF[1] = (f32x4){bb2[1][0], bb2[1][1], bb2[1][2], bb2[1][3]};
        a0[0] = a0[1] = a1[0] = a1[1] = a2[0] = a2[1] = vzero;

        bf16x8 bh, bl;
        split8(vF, bh, bl);
        aF[0] = mfma3(w2h[0], w2l[0], bh, bl, aF[0]);
        aF[1] = mfma3(w2h[1], w2l[1], bh, bl, aF[1]);
        split8(v0, bh, bl);
        a0[0] = mfma3(w2h[0], w2l[0], bh, bl, a0[0]);
        a0[1] = mfma3(w2h[1], w2l[1], bh, bl, a0[1]);
        split8(v1, bh, bl);
        a1[0] = mfma3(w2h[0], w2l[0], bh, bl, a1[0]);
        a1[1] = mfma3(w2h[1], w2l[1], bh, bl, a1[1]);
        split8(v2, bh, bl);
        a2[0] = mfma3(w2h[0], w2l[0], bh, bl, a2[0]);
        a2[1] = mfma3(w2h[1], w2l[1], bh, bl, a2[1]);

        // ---- boundary: act + diag-scale, in C-layout (stays in-register) ----
        #pragma unroll
        for (int h = 0; h < 2; ++h)
            #pragma unroll
            for (int r = 0; r < 4; ++r) {
                float s2v;
                aF[h][r] = act_hs(aF[h][r], s2v);   // h2
                a0[h][r] *= s2v;
                a1[h][r] *= s2v;
                a2[h][r] *= s2v;
            }

        // ---- layer 3: C-frags feed B directly (K-permuted weights) ----
        f32x4 zF[2], u0[2], u1[2], u2[2];
        zF[0] = (f32x4){bb3[0][0], bb3[0][1], bb3[0][2], bb3[0][3]};
        zF[1] = (f32x4){bb3[1][0], bb3[1][1], bb3[1][2], bb3[1][3]};
        u0[0] = u0[1] = u1[0] = u1[1] = u2[0] = u2[1] = vzero;

        split_cc(aF[0], aF[1], bh, bl);
        zF[0] = mfma3(w3h[0], w3l[0], bh, bl, zF[0]);
        zF[1] = mfma3(w3h[1], w3l[1], bh, bl, zF[1]);
        split_cc(a0[0], a0[1], bh, bl);
        u0[0] = mfma3(w3h[0], w3l[0], bh, bl, u0[0]);
        u0[1] = mfma3(w3h[1], w3l[1], bh, bl, u0[1]);
        split_cc(a1[0], a1[1], bh, bl);
        u1[0] = mfma3(w3h[0], w3l[0], bh, bl, u1[0]);
        u1[1] = mfma3(w3h[1], w3l[1], bh, bl, u1[1]);
        split_cc(a2[0], a2[1], bh, bl);
        u2[0] = mfma3(w3h[0], w3l[0], bh, bl, u2[0]);
        u2[1] = mfma3(w3h[1], w3l[1], bh, bl, u2[1]);

        // ---- layer 4 fused with trace combine (6 FMA/row) ----
        float o0 = 0.f, o1 = 0.f, o2 = 0.f;
        #pragma unroll
        for (int h = 0; h < 2; ++h)
            #pragma unroll
            for (int r = 0; r < 4; ++r) {
                const float s3v = sigmoid20(zF[h][r]);
                const float t0v = s3v * u0[h][r];
                const float t1v = s3v * u1[h][r];
                const float t2v = s3v * u2[h][r];
                const float w0 = w4r[h][r][0], w1 = w4r[h][r][1], w2 = w4r[h][r][2];
                o0 = fmaf(t1v, w0, fmaf(t2v, w1, o0));
                o1 = fmaf(-t0v, w0, fmaf(t2v, w2, o1));
                o2 = fmaf(-t0v, w1, fmaf(-t1v, w2, o2));
            }

        o0 += __shfl_xor(o0, 16); o0 += __shfl_xor(o0, 32);
        o1 += __shfl_xor(o1, 16); o1 += __shfl_xor(o1, 32);
        o2 += __shfl_xor(o2, 16); o2 += __shfl_xor(o2, 32);

        if (g == 0) {
            out[3 * s + 0] = o0;
            out[3 * s + 1] = o1;
            out[3 * s + 2] = o2;
        }
    }
}

extern "C" void kernel_launch(void* const* d_in, const int* in_sizes, int n_in,
                              void* d_out, int out_size, void* d_ws, size_t ws_size,
                              hipStream_t stream)
{
    const float* x  = (const float*)d_in[0];
    const float* W1 = (const float*)d_in[1];
    const float* b1 = (const float*)d_in[2];
    const float* W2 = (const float*)d_in[3];
    const float* b2 = (const float*)d_in[4];
    const float* W3 = (const float*)d_in[5];
    const float* b3 = (const float*)d_in[6];
    const float* W4 = (const float*)d_in[7];
    // d_in[8] = b4 unused: constant offset cancels in the Jacobian.
    float* out = (float*)d_out;

    const int N = in_sizes[0] / 3;
    const int blocks = 4096;   // grid-stride, ~1.9 tiles/wave: tail balance
    presdiv_kernel<<<blocks, NTHR, 0, stream>>>(x, W1, b1, W2, b2, W3, b3, W4, out, N);
}

// Round 8
// 153.979 us; speedup vs baseline: 6.6121x; 1.0486x over previous
//
#include <hip/hip_runtime.h>
#include <math.h>

#define NTHR 256
#define WAVES_PER_BLOCK 4

typedef __attribute__((ext_vector_type(8))) _Float16 f16x8;   // MFMA A/B frag (4 VGPRs)
typedef __attribute__((ext_vector_type(2))) _Float16 half2v;
typedef __attribute__((ext_vector_type(4))) float f32x4;      // MFMA C/D frag
typedef __attribute__((ext_vector_type(4))) unsigned uint4v;

#define CEXP 28.85390082f     // 20 * log2(e)
#define KLOG 0.03465735903f   // ln(2) / 20

// raw gfx950 transcendentals: v_exp_f32 is 2^x, v_log_f32 is log2(x)
#define EXP2F(v) __builtin_amdgcn_exp2f(v)
#define LOG2F(v) __builtin_amdgcn_logf(v)

// softplus(beta=20): h = max(z,0) + (ln2/20)*log2(1+e), e = 2^(-|CEXP*z|)
static __device__ __forceinline__ float act_hs(float z, float& s) {
    float cz = CEXP * z;
    float e  = EXP2F(-fabsf(cz));
    float p  = 1.0f + e;
    float r  = __builtin_amdgcn_rcpf(p);
    s = (z >= 0.0f) ? r : (1.0f - r);
    return fmaxf(z, 0.0f) + KLOG * LOG2F(p);
}
// select-free: exp2 overflow->inf, rcp(inf)->0 saturates correctly
static __device__ __forceinline__ float sigmoid20(float z) {
    float e = EXP2F(-CEXP * z);
    return __builtin_amdgcn_rcpf(1.0f + e);
}

// pack 2 floats -> 2 f16 in one v_cvt_pkrtz_f16_f32
static __device__ __forceinline__ unsigned pk(float a, float b) {
    return __builtin_bit_cast(unsigned, __builtin_amdgcn_cvt_pkrtz(a, b));
}

// tangent stream: single-f16 pack, 4 instr per 8 elements
static __device__ __forceinline__ f16x8 pack8(const float* v) {
    uint4v u = {pk(v[0], v[1]), pk(v[2], v[3]), pk(v[4], v[5]), pk(v[6], v[7])};
    return __builtin_bit_cast(f16x8, u);
}
// forward stream: f16 hi/lo split (residual ~2^-22), 6 instr per pair
static __device__ __forceinline__ void fsplit8(const float* v, f16x8& hi, f16x8& lo) {
    unsigned h[4], l[4];
    #pragma unroll
    for (int p = 0; p < 4; ++p) {
        float a = v[2 * p], b = v[2 * p + 1];
        unsigned hp = pk(a, b);
        half2v hh = __builtin_bit_cast(half2v, hp);
        h[p] = hp;
        l[p] = pk(a - (float)hh[0], b - (float)hh[1]);
    }
    hi = __builtin_bit_cast(f16x8, (uint4v){h[0], h[1], h[2], h[3]});
    lo = __builtin_bit_cast(f16x8, (uint4v){l[0], l[1], l[2], l[3]});
}

// C-frag pair -> layer-3 B operand (valid via the K-permuted layer-3 A-frag:
// f(g,j) = j<4 ? 4g+j : 16+4g+(j-4)).
static __device__ __forceinline__ void fsplit_cc(const f32x4& c0, const f32x4& c1,
                                                 f16x8& hi, f16x8& lo) {
    float v[8] = {c0[0], c0[1], c0[2], c0[3], c1[0], c1[1], c1[2], c1[3]};
    fsplit8(v, hi, lo);
}
static __device__ __forceinline__ f16x8 pack_cc(const f32x4& c0, const f32x4& c1) {
    uint4v u = {pk(c0[0], c0[1]), pk(c0[2], c0[3]), pk(c1[0], c1[1]), pk(c1[2], c1[3])};
    return __builtin_bit_cast(f16x8, u);
}

// forward: D += Wh*Bh + Wh*Bl + Wl*Bh (drop lo*lo)
static __device__ __forceinline__ f32x4 mfma3(f16x8 wh, f16x8 wl, f16x8 bh, f16x8 bl, f32x4 c) {
    c = __builtin_amdgcn_mfma_f32_16x16x32_f16(wh, bh, c, 0, 0, 0);
    c = __builtin_amdgcn_mfma_f32_16x16x32_f16(wh, bl, c, 0, 0, 0);
    c = __builtin_amdgcn_mfma_f32_16x16x32_f16(wl, bh, c, 0, 0, 0);
    return c;
}
// tangent: D += Wh*B + Wl*B (B single f16, err ~2^-11 -> passes ~1:1 to out)
static __device__ __forceinline__ f32x4 mfma2(f16x8 wh, f16x8 wl, f16x8 b, f32x4 c) {
    c = __builtin_amdgcn_mfma_f32_16x16x32_f16(wh, b, c, 0, 0, 0);
    c = __builtin_amdgcn_mfma_f32_16x16x32_f16(wl, b, c, 0, 0, 0);
    return c;
}

// setup-time scalar f16 split (RTN via cast)
static __device__ __forceinline__ void split1h(float v, _Float16& hi, _Float16& lo) {
    _Float16 h = (_Float16)v;
    hi = h;
    lo = (_Float16)(v - (float)h);
}

__global__ void __launch_bounds__(NTHR)
presdiv_kernel(const float* __restrict__ x,
               const float* __restrict__ W1, const float* __restrict__ b1,
               const float* __restrict__ W2, const float* __restrict__ b2,
               const float* __restrict__ W3, const float* __restrict__ b3,
               const float* __restrict__ W4,
               float* __restrict__ out, int N)
{
    const int lane = threadIdx.x & 63;
    const int wid  = threadIdx.x >> 6;
    const int n16  = lane & 15;        // sample-within-tile / MFMA col
    const int g    = lane >> 4;        // quad

    // ---- persistent weights (per lane), f16 hi/lo split ----
    f16x8 w2h[2], w2l[2], w3h[2], w3l[2];
    #pragma unroll
    for (int h = 0; h < 2; ++h) {
        #pragma unroll
        for (int j = 0; j < 8; ++j) {
            _Float16 hi, lo;
            const int k2 = g * 8 + j;
            split1h(W2[k2 * 32 + 16 * h + n16], hi, lo);
            w2h[h][j] = hi; w2l[h][j] = lo;
            const int k3 = (j < 4) ? (4 * g + j) : (16 + 4 * g + (j - 4));
            split1h(W3[k3 * 32 + 16 * h + n16], hi, lo);
            w3h[h][j] = hi; w3l[h][j] = lo;
        }
    }
    float w1r[3][8], bb1[8];
    #pragma unroll
    for (int j = 0; j < 8; ++j) {
        bb1[j] = b1[g * 8 + j];
        #pragma unroll
        for (int d = 0; d < 3; ++d) w1r[d][j] = W1[d * 32 + g * 8 + j];
    }
    float bb2[2][4], bb3[2][4], w4r[2][4][3];
    #pragma unroll
    for (int h = 0; h < 2; ++h)
        #pragma unroll
        for (int r = 0; r < 4; ++r) {
            const int row = 16 * h + 4 * g + r;
            bb2[h][r] = b2[row];
            bb3[h][r] = b3[row];
            #pragma unroll
            for (int k = 0; k < 3; ++k) w4r[h][r][k] = W4[row * 3 + k];
        }

    const int ntiles = (N + 15) >> 4;
    const int nwaves = gridDim.x * WAVES_PER_BLOCK;
    const f32x4 vzero = {0.f, 0.f, 0.f, 0.f};

    for (int tile = blockIdx.x * WAVES_PER_BLOCK + wid; tile < ntiles; tile += nwaves) {
        int s = tile * 16 + n16;
        if (s >= N) s = N - 1;
        const float x0 = x[3 * s + 0];
        const float x1 = x[3 * s + 1];
        const float x2 = x[3 * s + 2];

        // ---- layer 1 (exact fp32), directly in B-layout ----
        float vF[8], v0[8], v1[8], v2[8];
        #pragma unroll
        for (int j = 0; j < 8; ++j) {
            float z = bb1[j];
            z = fmaf(x0, w1r[0][j], z);
            z = fmaf(x1, w1r[1][j], z);
            z = fmaf(x2, w1r[2][j], z);
            float sg; vF[j] = act_hs(z, sg);
            v0[j] = sg * w1r[0][j];
            v1[j] = sg * w1r[1][j];
            v2[j] = sg * w1r[2][j];
        }

        // ---- layer 2 ----
        f32x4 aF[2], a0[2], a1[2], a2[2];
        aF[0] = (f32x4){bb2[0][0], bb2[0][1], bb2[0][2], bb2[0][3]};
        aF[1] = (f32x4){bb2[1][0], bb2[1][1], bb2[1][2], bb2[1][3]};
        a0[0] = a0[1] = a1[0] = a1[1] = a2[0] = a2[1] = vzero;

        f16x8 bh, bl;
        fsplit8(vF, bh, bl);                 // forward: full split
        aF[0] = mfma3(w2h[0], w2l[0], bh, bl, aF[0]);
        aF[1] = mfma3(w2h[1], w2l[1], bh, bl, aF[1]);
        f16x8 tb = pack8(v0);                // tangents: single f16
        a0[0] = mfma2(w2h[0], w2l[0], tb, a0[0]);
        a0[1] = mfma2(w2h[1], w2l[1], tb, a0[1]);
        tb = pack8(v1);
        a1[0] = mfma2(w2h[0], w2l[0], tb, a1[0]);
        a1[1] = mfma2(w2h[1], w2l[1], tb, a1[1]);
        tb = pack8(v2);
        a2[0] = mfma2(w2h[0], w2l[0], tb, a2[0]);
        a2[1] = mfma2(w2h[1], w2l[1], tb, a2[1]);

        // ---- boundary: act + diag-scale, in C-layout ----
        #pragma unroll
        for (int h = 0; h < 2; ++h)
            #pragma unroll
            for (int r = 0; r < 4; ++r) {
                float s2v;
                aF[h][r] = act_hs(aF[h][r], s2v);   // h2
                a0[h][r] *= s2v;
                a1[h][r] *= s2v;
                a2[h][r] *= s2v;
            }

        // ---- layer 3: C-frags feed B directly (K-permuted weights) ----
        f32x4 zF[2], u0[2], u1[2], u2[2];
        zF[0] = (f32x4){bb3[0][0], bb3[0][1], bb3[0][2], bb3[0][3]};
        zF[1] = (f32x4){bb3[1][0], bb3[1][1], bb3[1][2], bb3[1][3]};
        u0[0] = u0[1] = u1[0] = u1[1] = u2[0] = u2[1] = vzero;

        fsplit_cc(aF[0], aF[1], bh, bl);
        zF[0] = mfma3(w3h[0], w3l[0], bh, bl, zF[0]);
        zF[1] = mfma3(w3h[1], w3l[1], bh, bl, zF[1]);
        tb = pack_cc(a0[0], a0[1]);
        u0[0] = mfma2(w3h[0], w3l[0], tb, u0[0]);
        u0[1] = mfma2(w3h[1], w3l[1], tb, u0[1]);
        tb = pack_cc(a1[0], a1[1]);
        u1[0] = mfma2(w3h[0], w3l[0], tb, u1[0]);
        u1[1] = mfma2(w3h[1], w3l[1], tb, u1[1]);
        tb = pack_cc(a2[0], a2[1]);
        u2[0] = mfma2(w3h[0], w3l[0], tb, u2[0]);
        u2[1] = mfma2(w3h[1], w3l[1], tb, u2[1]);

        // ---- layer 4 fused with trace combine (6 FMA/row) ----
        float o0 = 0.f, o1 = 0.f, o2 = 0.f;
        #pragma unroll
        for (int h = 0; h < 2; ++h)
            #pragma unroll
            for (int r = 0; r < 4; ++r) {
                const float s3v = sigmoid20(zF[h][r]);
                const float t0v = s3v * u0[h][r];
                const float t1v = s3v * u1[h][r];
                const float t2v = s3v * u2[h][r];
                const float w0 = w4r[h][r][0], w1 = w4r[h][r][1], w2 = w4r[h][r][2];
                o0 = fmaf(t1v, w0, fmaf(t2v, w1, o0));
                o1 = fmaf(-t0v, w0, fmaf(t2v, w2, o1));
                o2 = fmaf(-t0v, w1, fmaf(-t1v, w2, o2));
            }

        o0 += __shfl_xor(o0, 16); o0 += __shfl_xor(o0, 32);
        o1 += __shfl_xor(o1, 16); o1 += __shfl_xor(o1, 32);
        o2 += __shfl_xor(o2, 16); o2 += __shfl_xor(o2, 32);

        if (g == 0) {
            out[3 * s + 0] = o0;
            out[3 * s + 1] = o1;
            out[3 * s + 2] = o2;
        }
    }
}

extern "C" void kernel_launch(void* const* d_in, const int* in_sizes, int n_in,
                              void* d_out, int out_size, void* d_ws, size_t ws_size,
                              hipStream_t stream)
{
    const float* x  = (const float*)d_in[0];
    const float* W1 = (const float*)d_in[1];
    const float* b1 = (const float*)d_in[2];
    const float* W2 = (const float*)d_in[3];
    const float* b2 = (const float*)d_in[4];
    const float* W3 = (const float*)d_in[5];
    const float* b3 = (const float*)d_in[6];
    const float* W4 = (const float*)d_in[7];
    // d_in[8] = b4 unused: constant offset cancels in the Jacobian.
    float* out = (float*)d_out;

    const int N = in_sizes[0] / 3;
    const int blocks = 4096;   // grid-stride, ~3.8 tiles/wave
    presdiv_kernel<<<blocks, NTHR, 0, stream>>>(x, W1, b1, W2, b2, W3, b3, W4, out, N);
}